// Round 2
// baseline (472.303 us; speedup 1.0000x reference)
//
#include <hip/hip_runtime.h>

typedef unsigned short u16;

constexpr int N    = 50000;
constexpr int E    = 800000;
constexpr int G    = 512;
constexpr int HC   = 256;   // H*C
constexpr int DIN  = 128;
constexpr int DENC = 256;
constexpr int DFC  = 320;   // DENC + C
constexpr int NBLK = (N + 1023) / 1024;

__device__ __forceinline__ float bf2f(u16 u) {
    return __uint_as_float(((unsigned)u) << 16);
}
__device__ __forceinline__ u16 f2bf(float f) {
    unsigned u = __float_as_uint(f);
    u += 0x7fffu + ((u >> 16) & 1u);
    return (u16)(u >> 16);
}
__device__ __forceinline__ float lrelu(float v, float s) {
    return v > 0.0f ? v : v * s;
}

// dtype-generic accessors (BF=true: bf16 u16; false: fp32)
template<bool BF> __device__ __forceinline__ float ld(const void* p, size_t i) {
    if constexpr (BF) return bf2f(((const u16*)p)[i]);
    else              return ((const float*)p)[i];
}
template<bool BF> __device__ __forceinline__ float4 ld4(const void* p, size_t i) { // i%4==0
    if constexpr (BF) {
        ushort4 v = ((const ushort4*)p)[i >> 2];
        return make_float4(bf2f(v.x), bf2f(v.y), bf2f(v.z), bf2f(v.w));
    } else {
        return ((const float4*)p)[i >> 2];
    }
}
template<bool BF> __device__ __forceinline__ void st(void* p, size_t i, float v) {
    if constexpr (BF) ((u16*)p)[i] = f2bf(v);
    else              ((float*)p)[i] = v;
}

// ---------------- dtype detector: bf16 stream -> ~100% exp fields in [100,140];
// fp32 read as u16 -> only ~58% (low mantissa halves uniform). flag 0=bf16, 1=fp32
__global__ void k_detect(const void* x, int* flag) {
    if (blockIdx.x == 0 && threadIdx.x == 0) {
        const u16* p = (const u16*)x;
        int ok = 0;
        for (int i = 0; i < 256; i++) {
            unsigned e = (p[i] >> 7) & 0xffu;
            if (e == 0u || (e >= 100u && e <= 140u)) ok++;
        }
        *flag = (ok >= 218) ? 0 : 1;
    }
}

// ---------------- Kernel 1: xl = x@Wl+bl, xr = x@Wr+br (fp32 accum, bf16 out)
template<bool BF>
__device__ void xlxr_body(const void* __restrict__ x, const void* __restrict__ Wl,
                          const void* __restrict__ bl, const void* __restrict__ Wr,
                          const void* __restrict__ br,
                          u16* __restrict__ xl, u16* __restrict__ xr) {
    __shared__ float xs[16][DIN];
    int b = blockIdx.x, t = threadIdx.x;
    int row0 = b * 16;
    size_t base = (size_t)row0 * DIN + (size_t)t * 8;
    float v[8];
    if constexpr (BF) {
        const ushort4* xp = (const ushort4*)x;
        ushort4 a0 = xp[base >> 2], a1 = xp[(base >> 2) + 1];
        v[0]=bf2f(a0.x); v[1]=bf2f(a0.y); v[2]=bf2f(a0.z); v[3]=bf2f(a0.w);
        v[4]=bf2f(a1.x); v[5]=bf2f(a1.y); v[6]=bf2f(a1.z); v[7]=bf2f(a1.w);
    } else {
        const float4* xp = (const float4*)x;
        float4 f0 = xp[base >> 2], f1 = xp[(base >> 2) + 1];
        v[0]=f0.x; v[1]=f0.y; v[2]=f0.z; v[3]=f0.w;
        v[4]=f1.x; v[5]=f1.y; v[6]=f1.z; v[7]=f1.w;
    }
    int m = t >> 4, k0 = (t & 15) * 8;
    #pragma unroll
    for (int i = 0; i < 8; i++) xs[m][k0 + i] = v[i];
    __syncthreads();
    float accl[16], accr[16];
    #pragma unroll
    for (int i = 0; i < 16; i++) { accl[i] = 0.f; accr[i] = 0.f; }
    for (int k = 0; k < DIN; k++) {
        float wl = ld<BF>(Wl, (size_t)k * HC + t);
        float wr = ld<BF>(Wr, (size_t)k * HC + t);
        #pragma unroll
        for (int i = 0; i < 16; i++) {
            float xv = xs[i][k];
            accl[i] = fmaf(xv, wl, accl[i]);
            accr[i] = fmaf(xv, wr, accr[i]);
        }
    }
    float blv = ld<BF>(bl, t), brv = ld<BF>(br, t);
    #pragma unroll
    for (int i = 0; i < 16; i++) {
        xl[(size_t)(row0 + i) * HC + t] = f2bf(accl[i] + blv);
        xr[(size_t)(row0 + i) * HC + t] = f2bf(accr[i] + brv);
    }
}

__global__ __launch_bounds__(256) void k_xlxr(
    const void* x, const void* Wl, const void* bl, const void* Wr, const void* br,
    u16* xl, u16* xr, const int* flag) {
    if (*flag == 0) xlxr_body<true>(x, Wl, bl, Wr, br, xl, xr);
    else            xlxr_body<false>(x, Wl, bl, Wr, br, xl, xr);
}

// ---------------- CSR build
__global__ void k_deg(const int* __restrict__ ei, int* __restrict__ deg) {
    int e = blockIdx.x * blockDim.x + threadIdx.x;
    if (e < E) {
        int d = ei[E + e];
        if ((unsigned)d < (unsigned)N) atomicAdd(&deg[d], 1);
    }
}

__global__ void k_chunksum(const int* __restrict__ deg, int* __restrict__ blocksum) {
    int b = blockIdx.x, t = threadIdx.x;
    int base = b * 1024 + t * 4;
    int s = 0;
    #pragma unroll
    for (int i = 0; i < 4; i++) { int idx = base + i; if (idx < N) s += deg[idx]; }
    for (int off = 32; off; off >>= 1) s += __shfl_down(s, off, 64);
    __shared__ int ls[4];
    int wave = t >> 6;
    if ((t & 63) == 0) ls[wave] = s;
    __syncthreads();
    if (t == 0) blocksum[b] = ls[0] + ls[1] + ls[2] + ls[3];
}

__global__ void k_scanoff(int* __restrict__ blocksum, int* __restrict__ rowptr) {
    if (threadIdx.x == 0 && blockIdx.x == 0) {
        int run = 0;
        for (int b = 0; b < NBLK; b++) { int v = blocksum[b]; blocksum[b] = run; run += v; }
        rowptr[N] = run;
    }
}

__global__ void k_scanwrite(const int* __restrict__ deg, const int* __restrict__ blocksum,
                            int* __restrict__ rowptr) {
    int b = blockIdx.x, t = threadIdx.x;
    int base = b * 1024 + t * 4;
    int v[4]; int s = 0;
    #pragma unroll
    for (int i = 0; i < 4; i++) { v[i] = (base + i < N) ? deg[base + i] : 0; s += v[i]; }
    int lane = t & 63, wave = t >> 6;
    int x = s;
    for (int off = 1; off < 64; off <<= 1) {
        int y = __shfl_up(x, off, 64);
        if (lane >= off) x += y;
    }
    __shared__ int wtot[4];
    if (lane == 63) wtot[wave] = x;
    __syncthreads();
    int woff = 0;
    for (int w = 0; w < wave; w++) woff += wtot[w];
    int run = blocksum[b] + woff + (x - s);
    #pragma unroll
    for (int i = 0; i < 4; i++) {
        int idx = base + i;
        if (idx < N) rowptr[idx] = run;
        run += v[i];
    }
}

__global__ void k_fill(const int* __restrict__ ei, const int* __restrict__ rowptr,
                       int* __restrict__ cursor, int* __restrict__ col) {
    int e = blockIdx.x * blockDim.x + threadIdx.x;
    if (e < E) {
        int d = ei[E + e];
        if ((unsigned)d < (unsigned)N) {
            int pos = atomicAdd(&cursor[d], 1);
            unsigned idx = (unsigned)(rowptr[d] + pos);
            if (idx < (unsigned)E) col[idx] = ei[e];   // src
        }
    }
}

// ---------------- GAT: one wave per dst node, local softmax, self-loop inline
template<bool BF>
__device__ void gat_body(const u16* __restrict__ xl, const u16* __restrict__ xr,
                         const int* __restrict__ rowptr, const int* __restrict__ col,
                         const void* __restrict__ att, const void* __restrict__ bias_gnn,
                         float* __restrict__ hnode) {
    int wid = (blockIdx.x * blockDim.x + threadIdx.x) >> 6;
    int lane = threadIdx.x & 63;
    if (wid >= N) return;
    int node = wid;

    const ushort4* xl4 = reinterpret_cast<const ushort4*>(xl);
    const ushort4* xr4 = reinterpret_cast<const ushort4*>(xr);

    ushort4 xrv = xr4[(size_t)node * 64 + lane];
    float r0 = bf2f(xrv.x), r1 = bf2f(xrv.y), r2 = bf2f(xrv.z), r3 = bf2f(xrv.w);
    float4 atv = ld4<BF>(att, (size_t)lane * 4);
    float t0 = atv.x, t1 = atv.y, t2 = atv.z, t3 = atv.w;

    float l = 0.f, a0 = 0.f, a1 = 0.f, a2 = 0.f, a3 = 0.f;
    int beg = rowptr[node], end = rowptr[node + 1];
    beg = max(0, min(beg, E));
    end = max(beg, min(end, E));
    for (int j = beg; j <= end; j++) {
        int src = node;                 // j == end -> self loop
        if (j < end) {
            int c = col[j];
            src = ((unsigned)c < (unsigned)N) ? c : node;
        }
        ushort4 xlv = xl4[(size_t)src * 64 + lane];
        float x0 = bf2f(xlv.x), x1 = bf2f(xlv.y), x2 = bf2f(xlv.z), x3 = bf2f(xlv.w);
        float s0 = lrelu(x0 + r0, 0.2f), s1 = lrelu(x1 + r1, 0.2f);
        float s2 = lrelu(x2 + r2, 0.2f), s3 = lrelu(x3 + r3, 0.2f);
        float p = fmaf(s0, t0, fmaf(s1, t1, fmaf(s2, t2, s3 * t3)));
        p += __shfl_xor(p, 1);
        p += __shfl_xor(p, 2);
        p += __shfl_xor(p, 4);
        p += __shfl_xor(p, 8);
        float w = __expf(fminf(p, 80.0f));
        l += w;
        a0 = fmaf(x0, w, a0); a1 = fmaf(x1, w, a1);
        a2 = fmaf(x2, w, a2); a3 = fmaf(x3, w, a3);
    }
    float inv = 1.0f / (l + 1e-16f);
    a0 *= inv; a1 *= inv; a2 *= inv; a3 *= inv;
    // mean over heads: sum lanes ^16 ^32, then /4
    a0 += __shfl_xor(a0, 16); a0 += __shfl_xor(a0, 32);
    a1 += __shfl_xor(a1, 16); a1 += __shfl_xor(a1, 32);
    a2 += __shfl_xor(a2, 16); a2 += __shfl_xor(a2, 32);
    a3 += __shfl_xor(a3, 16); a3 += __shfl_xor(a3, 32);
    if (lane < 16) {
        float4 bv = ld4<BF>(bias_gnn, (size_t)lane * 4);
        float4 o;
        o.x = lrelu(a0 * 0.25f + bv.x, 0.01f);
        o.y = lrelu(a1 * 0.25f + bv.y, 0.01f);
        o.z = lrelu(a2 * 0.25f + bv.z, 0.01f);
        o.w = lrelu(a3 * 0.25f + bv.w, 0.01f);
        reinterpret_cast<float4*>(hnode)[(size_t)node * 16 + lane] = o;
    }
}

__global__ __launch_bounds__(256) void k_gat(
    const u16* xl, const u16* xr, const int* rowptr, const int* col,
    const void* att, const void* bias_gnn, float* hnode, const int* flag) {
    if (*flag == 0) gat_body<true>(xl, xr, rowptr, col, att, bias_gnn, hnode);
    else            gat_body<false>(xl, xr, rowptr, col, att, bias_gnn, hnode);
}

// ---------------- per-graph mean pool (batch sorted)
__global__ void k_pool(const float* __restrict__ hnode, const int* __restrict__ batch,
                       float* __restrict__ hg) {
    int g = blockIdx.x, t = threadIdx.x;  // 64 threads
    int lo = 0, hi = N;
    while (lo < hi) { int mid = (lo + hi) >> 1; if (batch[mid] < g) lo = mid + 1; else hi = mid; }
    int s0 = lo;
    hi = N;
    while (lo < hi) { int mid = (lo + hi) >> 1; if (batch[mid] < g + 1) lo = mid + 1; else hi = mid; }
    int s1 = lo;
    float sum = 0.f;
    for (int n = s0; n < s1; n++) sum += hnode[(size_t)n * 64 + t];
    int cnt = s1 - s0; if (cnt < 1) cnt = 1;
    hg[g * 64 + t] = sum / (float)cnt;
}

// ---------------- final fc: out[g] = [hy[g], hg[g]] @ Wfc + bfc
template<bool BF>
__device__ void fc_body(const void* __restrict__ hy, const float* __restrict__ hg,
                        const void* __restrict__ Wfc, const void* __restrict__ bfc,
                        void* __restrict__ out) {
    int g = blockIdx.x, t = threadIdx.x;
    __shared__ float cat[DFC];
    cat[t] = ld<BF>(hy, (size_t)g * DENC + t);
    if (t < 64) cat[DENC + t] = hg[g * 64 + t];
    __syncthreads();
    float acc = ld<BF>(bfc, t);
    for (int k = 0; k < DFC; k++) acc = fmaf(cat[k], ld<BF>(Wfc, (size_t)k * DENC + t), acc);
    st<BF>(out, (size_t)g * DENC + t, acc);
}

__global__ __launch_bounds__(256) void k_fc(
    const void* hy, const float* hg, const void* Wfc, const void* bfc,
    void* out, const int* flag) {
    if (*flag == 0) fc_body<true>(hy, hg, Wfc, bfc, out);
    else            fc_body<false>(hy, hg, Wfc, bfc, out);
}

extern "C" void kernel_launch(void* const* d_in, const int* in_sizes, int n_in,
                              void* d_out, int out_size, void* d_ws, size_t ws_size,
                              hipStream_t stream) {
    const void* hy   = d_in[0];
    const void* x    = d_in[1];
    const int*  ei   = (const int*)d_in[2];
    const int*  batch= (const int*)d_in[3];
    const void* Wl   = d_in[4];
    const void* bl   = d_in[5];
    const void* Wr   = d_in[6];
    const void* br   = d_in[7];
    const void* att  = d_in[8];
    const void* bias = d_in[9];
    const void* Wfc  = d_in[10];
    const void* bfc  = d_in[11];

    char* w = (char*)d_ws;
    u16*  xl      = (u16*)w;   w += (size_t)N * HC * 2;
    u16*  xr      = (u16*)w;   w += (size_t)N * HC * 2;
    float* hnode  = (float*)w; w += (size_t)N * 64 * 4;
    float* hg     = (float*)w; w += (size_t)G * 64 * 4;
    int*  col     = (int*)w;   w += (size_t)E * 4;
    int*  rowptr  = (int*)w;   w += ((size_t)N + 16) * 4;
    int*  blocksum= (int*)w;   w += 64 * 4;
    int*  flag    = (int*)w;   w += 64 * 4;
    int*  deg     = (int*)w;   w += (size_t)N * 4;
    int*  cursor  = (int*)w;   w += (size_t)N * 4;
    // total ~68 MB

    // zero deg + cursor (adjacent)
    hipMemsetAsync(deg, 0, (size_t)2 * N * 4, stream);

    k_detect<<<1, 64, 0, stream>>>(x, flag);
    k_xlxr<<<N / 16, 256, 0, stream>>>(x, Wl, bl, Wr, br, xl, xr, flag);
    k_deg<<<(E + 255) / 256, 256, 0, stream>>>(ei, deg);
    k_chunksum<<<NBLK, 256, 0, stream>>>(deg, blocksum);
    k_scanoff<<<1, 64, 0, stream>>>(blocksum, rowptr);
    k_scanwrite<<<NBLK, 256, 0, stream>>>(deg, blocksum, rowptr);
    k_fill<<<(E + 255) / 256, 256, 0, stream>>>(ei, rowptr, cursor, col);
    k_gat<<<(N * 64 + 255) / 256, 256, 0, stream>>>(xl, xr, rowptr, col, att, bias, hnode, flag);
    k_pool<<<G, 64, 0, stream>>>(hnode, batch, hg);
    k_fc<<<G, 256, 0, stream>>>(hy, hg, Wfc, bfc, d_out, flag);
}